// Round 1
// baseline (403.720 us; speedup 1.0000x reference)
//
#include <hip/hip_runtime.h>
#include <math.h>

// TrafficAugmentation: per-row burst-chain simulation.
// One block per row (S=4096 packets), 256 threads, 16 positions/thread.
//
// Correctness-critical: burst-end decisions replicate the reference's exact
// fp32 op order (r = rtts[s]; r -= d[j] serially; stop at r <= 0). Burst byte
// sums accumulate in increasing j order from 0.0f (segment_sum order).
// rem = buf - n_full*1448.0f is exact under FMA contraction since
// n_full*1448 < 2^24.

#define S_LEN 4096
#define BLOCK 256
#define PER   16          // S_LEN / BLOCK
#define MSSF  1448.0f

// LDS layout (byte offsets into one shared buffer), total 57376 B -> 2 blocks/CU
#define OFF_DELAY 0        // float[4096]  (phase1: delays; phase3: out row)
#define OFF_X     16384    // float[4096]
#define OFF_RTT   32768    // float[4096]  (phase2+: jumpB u16[4097] + mark u8[4097])
#define OFF_JB    32768
#define OFF_MARK  40968
#define OFF_JA    49152    // u16[4097]
#define OFF_WSUM  57352    // int[4]
#define SMEM_SIZE 57376

__global__ __launch_bounds__(BLOCK, 2) void traffic_kernel(
    const float* __restrict__ gx,
    const float* __restrict__ gd,
    const float* __restrict__ gr,
    float* __restrict__ gout)
{
    __shared__ __align__(16) unsigned char smem[SMEM_SIZE];
    float*          s_delay = (float*)(smem + OFF_DELAY);
    float*          s_x     = (float*)(smem + OFF_X);
    float*          s_rtt   = (float*)(smem + OFF_RTT);
    unsigned short* jA      = (unsigned short*)(smem + OFF_JA);
    unsigned short* jB      = (unsigned short*)(smem + OFF_JB);
    unsigned char*  s_mark  = (unsigned char*)(smem + OFF_MARK);
    int*            s_wsum  = (int*)(smem + OFF_WSUM);
    float*          s_out   = (float*)(smem + OFF_DELAY);

    const int tid = threadIdx.x;
    const size_t rowoff = (size_t)blockIdx.x * S_LEN;
    const float* px = gx + rowoff;
    const float* pd = gd + rowoff;
    const float* pr = gr + rowoff;

    // ---- Phase 0: stage row into LDS (coalesced) ----
    for (int i = tid; i < S_LEN; i += BLOCK) {
        s_x[i]     = px[i];
        s_delay[i] = pd[i];
        s_rtt[i]   = pr[i];
    }
    __syncthreads();

    // ---- Phase 1: per-position burst-end + burst byte-sum (exact fp32 order) ----
    const int base = tid * PER;
    float bsum[PER];
    unsigned int aliveMask = 0;
#pragma unroll
    for (int i = 0; i < PER; ++i) {
        int s0 = base + i;
        float xv = s_x[s0];
        float sum = 0.0f;
        int nx = S_LEN;
        if (xv > 0.0f) {
            aliveMask |= (1u << i);
            float r = s_rtt[s0];
            int j = s0;
            while (true) {
                r   -= s_delay[j];   // matches reference r_next = r - d[j]
                sum += s_x[j];       // segment_sum order: increasing j from 0.0f
                if (r <= 0.0f) { nx = j + 1; break; }
                ++j;
                if (j >= S_LEN) break;  // burst consumes to end of row
            }
        }
        bsum[i] = sum;
        jA[s0] = (unsigned short)nx;
    }
    __syncthreads();   // phase 1 done: rtt region may now be reused (jB, mark)

    // ---- Phase 2: mark chain-reachable positions via pointer doubling ----
    for (int i = tid; i <= S_LEN; i += BLOCK) s_mark[i] = 0;
    if (tid == 0) { s_mark[0] = 1; jA[S_LEN] = S_LEN; jB[S_LEN] = S_LEN; }
    __syncthreads();

    unsigned short* ja = jA;
    unsigned short* jb = jB;
    for (int k = 0; k < 12; ++k) {
        // mark: every marked node marks its 2^k-successor (benign write-1 races;
        // after round k all chain indices < 2^(k+1) are marked)
#pragma unroll
        for (int i = 0; i < PER; ++i) {
            int s0 = base + i;
            if (s_mark[s0]) s_mark[ja[s0]] = 1;
        }
        __syncthreads();
        if (k < 11) {
#pragma unroll
            for (int i = 0; i < PER; ++i) {
                int s0 = base + i;
                jb[s0] = ja[ja[s0]];   // jump_{k+1} = jump_k ∘ jump_k (sentinel S stays S)
            }
            __syncthreads();
            unsigned short* t = ja; ja = jb; jb = t;
        }
    }

    // ---- Phase 3: per-burst output counts + block exclusive scan ----
    int loc[PER];
    int tsum = 0;
#pragma unroll
    for (int i = 0; i < PER; ++i) {
        int s0 = base + i;
        int c = 0;
        if (s_mark[s0] && ((aliveMask >> i) & 1u)) {
            float buf = bsum[i];
            int nf = (int)ceilf(buf / MSSF) - 1;
            if (nf < 0) nf = 0;
            float rem = buf - (float)nf * MSSF;   // exact mul (< 2^24), FMA-safe
            c = nf + (rem > 0.0f ? 1 : 0);
        }
        loc[i] = tsum;
        tsum += c;
    }
    int lane = tid & 63;
    int wv   = tid >> 6;
    int v = tsum;
    for (int off = 1; off < 64; off <<= 1) {
        int u = __shfl_up(v, off, 64);
        if (lane >= off) v += u;
    }
    if (lane == 63) s_wsum[wv] = v;
    __syncthreads();
    int woff = 0;
    for (int w = 0; w < wv; ++w) woff += s_wsum[w];
    int texcl = woff + v - tsum;   // exclusive prefix for this thread's first slot

    // ---- Phase 4: build output row in LDS, then coalesced store ----
    for (int i = tid; i < S_LEN; i += BLOCK) s_out[i] = 0.0f;
    __syncthreads();
#pragma unroll
    for (int i = 0; i < PER; ++i) {
        int s0 = base + i;
        if (s_mark[s0] && ((aliveMask >> i) & 1u)) {
            float buf = bsum[i];
            int nf = (int)ceilf(buf / MSSF) - 1;
            if (nf < 0) nf = 0;
            float rem = buf - (float)nf * MSSF;
            int o = texcl + loc[i];
            int e = o + nf; if (e > S_LEN) e = S_LEN;     // truncation == OOB drop
            for (int p = o; p < e; ++p) s_out[p] = MSSF;
            int rp = o + nf;
            if (rem > 0.0f && rp < S_LEN) s_out[rp] = rem;
        }
    }
    __syncthreads();
    float* po = gout + rowoff;
    for (int i = tid; i < S_LEN; i += BLOCK) po[i] = s_out[i];
}

extern "C" void kernel_launch(void* const* d_in, const int* in_sizes, int n_in,
                              void* d_out, int out_size, void* d_ws, size_t ws_size,
                              hipStream_t stream) {
    const float* x      = (const float*)d_in[0];
    const float* delays = (const float*)d_in[1];
    const float* rtts   = (const float*)d_in[2];
    float* out = (float*)d_out;
    int rows = in_sizes[0] / S_LEN;   // B = 2048
    traffic_kernel<<<rows, BLOCK, 0, stream>>>(x, delays, rtts, out);
}

// Round 2
// 321.792 us; speedup vs baseline: 1.2546x; 1.2546x over previous
//
#include <hip/hip_runtime.h>
#include <math.h>

// TrafficAugmentation: per-row burst-chain simulation. One block per row
// (S=4096), 256 threads, 16 positions/thread (blocked ownership).
//
// R2: all LDS arrays XOR-swizzled to kill the stride-16 32-way bank
// conflicts that dominated R1 (SQ_LDS_BANK_CONFLICT 1.05e8); pointer
// doubling replaced by exit-compressed 8-round doubling over segment-entry
// nodes (bitmask marks); phase-1 walk flattened per-lane; LDS 50.2 KB ->
// 3 blocks/CU.
//
// Exactness: burst ends replicate reference's serial fp32 r -= d[j]; burst
// sums re-walked in increasing-j order; rem = buf - nf*1448.0f exact.

#define S_LEN 4096
#define BLOCK 256
#define PER   16
#define MSSF  1448.0f

// LDS layout
#define OFF_X    0        // f32[4096] swizzled s4  (reused as s_out, plain, phase 4)
#define OFF_DLY  16384    // f32[4096] swizzled s4
#define OFF_NXT  32768    // u16[4097] swizzled s2
#define OFF_JMP  40968    // u16[4097] swizzled s2
#define OFF_MRK  49168    // u32[256] mark bitmask per 16-segment
#define OFF_WS   50192    // i32[4]
#define SMEM_SZ  50208

// swizzles: blocked access p=16t+j -> bank = 16(t&1) | (j ^ ((t>>1)&15))
// (f32) resp. derived 2-way pattern (u16): conflict-free. Bijective on [0,4096],
// fixed point at 4096 (sentinel).
__device__ __forceinline__ int s4i(int p) { return p ^ ((p >> 5) & 15); }
__device__ __forceinline__ int s2i(int p) { return p ^ (((p >> 6) & 15) << 1); }

__global__ __launch_bounds__(BLOCK, 3) void traffic_kernel(
    const float* __restrict__ gx,
    const float* __restrict__ gd,
    const float* __restrict__ gr,
    float* __restrict__ gout)
{
    __shared__ __align__(16) unsigned char smem[SMEM_SZ];
    float*          s_x   = (float*)(smem + OFF_X);
    float*          s_dly = (float*)(smem + OFF_DLY);
    unsigned short* s_nxt = (unsigned short*)(smem + OFF_NXT);
    unsigned short* s_jmp = (unsigned short*)(smem + OFF_JMP);
    unsigned*       s_mrk = (unsigned*)(smem + OFF_MRK);
    int*            s_ws  = (int*)(smem + OFF_WS);
    float*          s_out = (float*)(smem + OFF_X);

    const int tid  = threadIdx.x;
    const int base = tid * PER;
    const size_t rowoff = (size_t)blockIdx.x * S_LEN;
    const float* px = gx + rowoff;
    const float* pd = gd + rowoff;
    const float* pr = gr + rowoff;

    // ---- rtt for own 16 positions -> registers (coalesced float4 loads) ----
    float rt[PER];
    {
        const float4* p4 = (const float4*)(pr + base);
        float4 a = p4[0], b = p4[1], c = p4[2], d = p4[3];
        rt[0]=a.x;  rt[1]=a.y;  rt[2]=a.z;  rt[3]=a.w;
        rt[4]=b.x;  rt[5]=b.y;  rt[6]=b.z;  rt[7]=b.w;
        rt[8]=c.x;  rt[9]=c.y;  rt[10]=c.z; rt[11]=c.w;
        rt[12]=d.x; rt[13]=d.y; rt[14]=d.z; rt[15]=d.w;
    }

    // ---- Phase 0: stage x, delays into swizzled LDS ----
    {
        const float4* px4 = (const float4*)px;
        const float4* pd4 = (const float4*)pd;
        for (int q = tid; q < S_LEN / 4; q += BLOCK) {
            float4 v = px4[q], w = pd4[q];
            int p0 = q << 2;
            s_x[s4i(p0 + 0)] = v.x; s_x[s4i(p0 + 1)] = v.y;
            s_x[s4i(p0 + 2)] = v.z; s_x[s4i(p0 + 3)] = v.w;
            s_dly[s4i(p0 + 0)] = w.x; s_dly[s4i(p0 + 1)] = w.y;
            s_dly[s4i(p0 + 2)] = w.z; s_dly[s4i(p0 + 3)] = w.w;
        }
    }
    __syncthreads();

    // ---- Phase 1: flattened per-lane burst walk; writes nxt[p] for all own
    // positions. nxt = j+1 of ending packet, or S if runs off row / dead start.
    unsigned alive = 0;
    {
        int i = 0;
        int j = base;
        bool ini = true;
        float r = 0.0f;
        while (i < PER) {
            if (ini) {
                float xv = s_x[s4i(j)];
                if (xv <= 0.0f) {            // dead start: chain stops here
                    s_nxt[s2i(j)] = (unsigned short)S_LEN;
                    ++i; j = base + i;
                    continue;
                }
                alive |= (1u << i);
                float rv = rt[0];
#pragma unroll
                for (int ii = 1; ii < PER; ++ii) rv = (i == ii) ? rt[ii] : rv;
                r = rv;
                ini = false;
            }
            r -= s_dly[s4i(j)];              // exact reference op order
            ++j;
            if (r <= 0.0f || j >= S_LEN) {   // both cases: nxt = j (== S if ran off)
                s_nxt[s2i(base + i)] = (unsigned short)j;
                ++i; j = base + i;
                ini = true;
            }
        }
    }
    __syncthreads();

    // ---- Phase 2a: exit compression. jmp[p] = first chain hop from p that
    // leaves p's 16-segment (backward fold, own segment only).
#pragma unroll
    for (int i = PER - 1; i >= 0; --i) {
        int p = base + i;
        int v = s_nxt[s2i(p)];               // v > p
        int e = (v >= base + PER) ? v : (int)s_jmp[s2i(v)];
        s_jmp[s2i(p)] = (unsigned short)e;
    }
    if (tid == 0) s_jmp[4096] = 4096;        // sentinel (s2i(4096)==4096)
    s_mrk[tid] = (tid == 0) ? 1u : 0u;       // mark position 0
    __syncthreads();

    // ---- Phase 2b: 8-round doubling over exit-chain (<=256 nodes, <=1 per
    // segment -> mark bitmask word per segment has <=1 bit; races benign).
    for (int k = 0; k < 8; ++k) {
        unsigned m = s_mrk[tid];
        int q = -1;
        if (m) {
            int p = (tid << 4) + (__ffs(m) - 1);
            int e = s_jmp[s2i(p)];
            if (e < S_LEN) q = e;
        }
        if (k < 7) {
            int own[PER], nv[PER];
#pragma unroll
            for (int i = 0; i < PER; ++i) own[i] = s_jmp[s2i(base + i)];
#pragma unroll
            for (int i = 0; i < PER; ++i) nv[i] = s_jmp[s2i(own[i])];
            __syncthreads();
            if (q >= 0) atomicOr(&s_mrk[q >> 4], 1u << (q & 15));
#pragma unroll
            for (int i = 0; i < PER; ++i) s_jmp[s2i(base + i)] = (unsigned short)nv[i];
            __syncthreads();
        } else {
            __syncthreads();
            if (q >= 0) atomicOr(&s_mrk[q >> 4], 1u << (q & 15));
            __syncthreads();
        }
    }

    // ---- Phase 2c: expand entry mark to all chain nodes in own segment ----
    unsigned lm = 0;
    {
        unsigned m = s_mrk[tid];
        if (m) {
            int p = (tid << 4) + (__ffs(m) - 1);
            while (p < base + PER) {
                lm |= 1u << (p - base);
                p = (int)s_nxt[s2i(p)];
            }
        }
    }

    // ---- Phase 3: burst sums (re-walk marked bursts only, increasing j ->
    // exact segment_sum order), counts, block-wide exclusive scan.
    float bsum[PER];
    int   loc[PER];
    int tsum = 0;
    unsigned use = lm & alive;
#pragma unroll
    for (int i = 0; i < PER; ++i) {
        int c = 0; float buf = 0.0f;
        if ((use >> i) & 1u) {
            int p = base + i;
            int e = (int)s_nxt[s2i(p)];
            float sum = 0.0f;
            for (int j = p; j < e; ++j) sum += s_x[s4i(j)];
            buf = sum;
            int nf = (int)ceilf(buf / MSSF) - 1; if (nf < 0) nf = 0;
            float rem = buf - (float)nf * MSSF;  // exact: nf*1448 < 2^24
            c = nf + (rem > 0.0f ? 1 : 0);
        }
        bsum[i] = buf; loc[i] = tsum; tsum += c;
    }
    {
        int lane = tid & 63, wv = tid >> 6;
        int v = tsum;
        for (int off = 1; off < 64; off <<= 1) {
            int u = __shfl_up(v, off, 64);
            if (lane >= off) v += u;
        }
        if (lane == 63) s_ws[wv] = v;
        __syncthreads();                       // also fences phase-3 s_x reads
        int woff = 0;
        for (int w = 0; w < wv; ++w) woff += s_ws[w];
        int texcl = woff + v - tsum;

        // ---- Phase 4: build output row (plain layout, overlays s_x) ----
        {
            float4* z4 = (float4*)s_out;
            float4 zz; zz.x = zz.y = zz.z = zz.w = 0.0f;
            for (int q2 = tid; q2 < S_LEN / 4; q2 += BLOCK) z4[q2] = zz;
        }
        __syncthreads();
#pragma unroll
        for (int i = 0; i < PER; ++i) {
            if ((use >> i) & 1u) {
                float buf = bsum[i];
                int nf = (int)ceilf(buf / MSSF) - 1; if (nf < 0) nf = 0;
                float rem = buf - (float)nf * MSSF;
                int o = texcl + loc[i];
                int e = o + nf; if (e > S_LEN) e = S_LEN;  // OOB drop == truncation
                for (int p = o; p < e; ++p) s_out[p] = MSSF;
                int rp = o + nf;
                if (rem > 0.0f && rp < S_LEN) s_out[rp] = rem;
            }
        }
        __syncthreads();
        float* po = gout + rowoff;
        float4* po4 = (float4*)po;
        float4* so4 = (float4*)s_out;
        for (int q2 = tid; q2 < S_LEN / 4; q2 += BLOCK) po4[q2] = so4[q2];
    }
}

extern "C" void kernel_launch(void* const* d_in, const int* in_sizes, int n_in,
                              void* d_out, int out_size, void* d_ws, size_t ws_size,
                              hipStream_t stream) {
    const float* x      = (const float*)d_in[0];
    const float* delays = (const float*)d_in[1];
    const float* rtts   = (const float*)d_in[2];
    float* out = (float*)d_out;
    int rows = in_sizes[0] / S_LEN;   // B = 2048
    traffic_kernel<<<rows, BLOCK, 0, stream>>>(x, delays, rtts, out);
}

// Round 3
// 209.354 us; speedup vs baseline: 1.9284x; 1.5371x over previous
//
#include <hip/hip_runtime.h>
#include <math.h>

// TrafficAugmentation R3. One block per row (S=4096), 256 threads.
// Phase 1 (walks): CYCLIC ownership (thread t owns {t+256i}) -> plain-layout
//   conflict-free LDS reads (lockstep lanes stay consecutive), 4-ahead unroll
//   cuts the dependent-latency chain 4x, zero swizzle VALU.
// Phases 2-4 (segments): BLOCKED mapping (thread t = segment [16t,16t+16)).
// LDS 25.8 KB (jmp/out overlay dead dly region; x read from global/L1)
//   -> 6 blocks/CU, 24 waves/CU.
// Exactness: serial fp32 r-=d[j] order preserved (4-ahead computes r1..r4 as
// chained subs, picks FIRST k with r_k<=0); burst sums serial increasing-j;
// rem = buf - nf*1448.0f exact (nf*1448 < 2^24, FMA-safe).

#define S_LEN 4096
#define BLOCK 256
#define PER   16
#define MSSF  1448.0f

// LDS: region A f32[4100] = dly(ph0-1) / jmp u16[4097](ph2) / out f32[4096](ph4)
#define OFF_A    0
#define OFF_NXT  16400    // u16[4097], s2-swizzled
#define OFF_MRK  24800    // u32[256] per-segment mark bitmask
#define OFF_WS   25824    // i32[4]
#define SMEM_SZ  25840

// u16 swizzle for blocked stride-16 access; preserves bit0 (pairs stay
// adjacent -> u32 paired access legal); fixed point at 4096 (sentinel).
__device__ __forceinline__ int s2i(int p) { return p ^ (((p >> 6) & 15) << 1); }

__global__ __launch_bounds__(BLOCK, 6) void traffic_kernel(
    const float* __restrict__ gx,
    const float* __restrict__ gd,
    const float* __restrict__ gr,
    float* __restrict__ gout)
{
    __shared__ __align__(16) unsigned char smem[SMEM_SZ];
    float*          s_dly = (float*)(smem + OFF_A);
    unsigned short* s_jmp = (unsigned short*)(smem + OFF_A);
    float*          s_out = (float*)(smem + OFF_A);
    unsigned short* s_nxt = (unsigned short*)(smem + OFF_NXT);
    unsigned*       s_mrk = (unsigned*)(smem + OFF_MRK);
    int*            s_ws  = (int*)(smem + OFF_WS);

    const int tid = threadIdx.x;
    const size_t rowoff = (size_t)blockIdx.x * S_LEN;
    const float* px = gx + rowoff;
    const float* pd = gd + rowoff;
    const float* pr = gr + rowoff;

    // ---- Phase 0: stage delays (plain), pad with -1e30 so the 4-ahead
    // window never falsely terminates past row end (r - (-1e30) stays > 0).
    {
        const float4* pd4 = (const float4*)pd;
        float4* s4 = (float4*)s_dly;
        for (int q = tid; q < S_LEN / 4; q += BLOCK) s4[q] = pd4[q];
        if (tid < 4) s_dly[S_LEN + tid] = -1.0e30f;
    }
    // rtts + alive bits for own cyclic positions (coalesced, latency overlapped)
    float rt[PER];
    unsigned alive = 0;
#pragma unroll
    for (int i = 0; i < PER; ++i) rt[i] = pr[tid + (i << 8)];
#pragma unroll
    for (int i = 0; i < PER; ++i) alive |= (px[tid + (i << 8)] > 0.0f) ? (1u << i) : 0u;
    __syncthreads();

    // ---- Phase 1: 4-ahead lockstep walks; all active lanes advance +4/round
    // so lane addresses stay consecutive (conflict-free plain layout).
#pragma unroll
    for (int i = 0; i < PER; ++i) {
        int p0 = tid + (i << 8);
        int j = p0;
        float r = rt[i];
        int nx;
        while (true) {
            float d0 = s_dly[j];
            float d1 = s_dly[j + 1];
            float d2 = s_dly[j + 2];
            float d3 = s_dly[j + 3];
            float r1 = r - d0;          // exact reference op order
            float r2 = r1 - d1;
            float r3 = r2 - d2;
            float r4 = r3 - d3;
            int kk = (r1 <= 0.0f) ? 1 : (r2 <= 0.0f) ? 2 :
                     (r3 <= 0.0f) ? 3 : (r4 <= 0.0f) ? 4 : 0;
            if (kk) { nx = j + kk; break; }
            j += 4;
            if (j >= S_LEN) { nx = S_LEN; break; }
            r = r4;
        }
        if (!((alive >> i) & 1u)) nx = S_LEN;   // dead start: chain stops here
        s_nxt[s2i(p0)] = (unsigned short)nx;
    }
    __syncthreads();

    // ---- Phase 2a: segment exit compression (thread t = segment t).
    // jmp[p] = first nxt-hop leaving p's 16-segment. own[] mirrors in regs.
    const int sb = tid << 4;
    int own[PER];
    if (tid == 0) s_jmp[4096] = (unsigned short)4096;   // sentinel
#pragma unroll
    for (int i = PER - 1; i >= 0; --i) {
        int p = sb + i;
        int v = (int)s_nxt[s2i(p)];
        int e = (v >= sb + PER) ? v : (int)s_jmp[s2i(v)];  // own-seg RAW ok
        s_jmp[s2i(p)] = (unsigned short)e;
        own[i] = e;
    }
    s_mrk[tid] = (tid == 0) ? 1u : 0u;
    __syncthreads();

    // ---- Phase 2b: 8-round pointer doubling over exit chain (<=256 nodes,
    // <=1 per segment since exit hops strictly increase segment index).
    // own[] in registers: only the random gather + paired write hit LDS.
    for (int k = 0; k < 8; ++k) {
        unsigned m = s_mrk[tid];
        int q = -1;
        if (m) {
            int p = sb + (__ffs(m) - 1);
            int e = (int)s_jmp[s2i(p)];
            if (e < S_LEN) q = e;
        }
        int nv[PER];
        if (k < 7) {
#pragma unroll
            for (int i = 0; i < PER; ++i) nv[i] = (int)s_jmp[s2i(own[i])];
        }
        __syncthreads();   // all round-k reads complete
        if (q >= 0) atomicOr(&s_mrk[q >> 4], 1u << (q & 15));
        if (k < 7) {
#pragma unroll
            for (int h = 0; h < PER / 2; ++h) {   // paired u32 writes (s2i keeps pairs adjacent)
                unsigned w = (unsigned)nv[2 * h] | ((unsigned)nv[2 * h + 1] << 16);
                *(unsigned*)&s_jmp[s2i(sb + 2 * h)] = w;
            }
#pragma unroll
            for (int i = 0; i < PER; ++i) own[i] = nv[i];
        }
        __syncthreads();
    }

    // ---- Phase 2c: expand segment-entry mark to burst starts in segment ----
    unsigned lm = 0;
    {
        unsigned m = s_mrk[tid];
        if (m) {
            int p = sb + (__ffs(m) - 1);
            while (p < sb + PER) {
                lm |= 1u << (p - sb);
                p = (int)s_nxt[s2i(p)];
            }
        }
    }

    // ---- Phase 3: burst sums (global x, L1-resident after first touches),
    // serial increasing-j adds; per-thread counts.
    float bsum[PER];
    unsigned use = 0;
    int tsum = 0;
#pragma unroll
    for (int i = 0; i < PER; ++i) {
        float buf = 0.0f;
        int c = 0;
        if ((lm >> i) & 1u) {
            int p = sb + i;
            int e = (int)s_nxt[s2i(p)];
            float xp = px[p];
            if (xp > 0.0f) {             // dead start -> not a burst
                use |= 1u << i;
                float sum = xp;
                for (int j = p + 1; j < e; ++j) sum += px[j];
                buf = sum;
                int nf = (int)ceilf(buf / MSSF) - 1; if (nf < 0) nf = 0;
                float rem = buf - (float)nf * MSSF;   // exact
                c = nf + (rem > 0.0f ? 1 : 0);
            }
        }
        bsum[i] = buf;
        tsum += c;
    }

    // ---- block exclusive scan of counts (bursts ordered by start p) ----
    int texcl;
    {
        int lane = tid & 63, wv = tid >> 6;
        int v = tsum;
        for (int off = 1; off < 64; off <<= 1) {
            int u = __shfl_up(v, off, 64);
            if (lane >= off) v += u;
        }
        if (lane == 63) s_ws[wv] = v;
        __syncthreads();
        int woff = 0;
        for (int w = 0; w < wv; ++w) woff += s_ws[w];
        texcl = woff + v - tsum;
    }

    // ---- Phase 4: build output row in A (jmp dead), coalesced store ----
    {
        float4* z4 = (float4*)s_out;
        float4 zz; zz.x = zz.y = zz.z = zz.w = 0.0f;
        for (int q = tid; q < S_LEN / 4; q += BLOCK) z4[q] = zz;
    }
    __syncthreads();
    {
        int o = texcl;
#pragma unroll
        for (int i = 0; i < PER; ++i) {
            if ((use >> i) & 1u) {
                float buf = bsum[i];
                int nf = (int)ceilf(buf / MSSF) - 1; if (nf < 0) nf = 0;
                float rem = buf - (float)nf * MSSF;
                int e = o + nf; if (e > S_LEN) e = S_LEN;   // OOB drop == truncation
                for (int p2 = o; p2 < e; ++p2) s_out[p2] = MSSF;
                int rp = o + nf;
                if (rem > 0.0f && rp < S_LEN) s_out[rp] = rem;
                o += nf + (rem > 0.0f ? 1 : 0);
            }
        }
    }
    __syncthreads();
    {
        float4* po4 = (float4*)(gout + rowoff);
        float4* so4 = (float4*)s_out;
        for (int q = tid; q < S_LEN / 4; q += BLOCK) po4[q] = so4[q];
    }
}

extern "C" void kernel_launch(void* const* d_in, const int* in_sizes, int n_in,
                              void* d_out, int out_size, void* d_ws, size_t ws_size,
                              hipStream_t stream) {
    const float* x      = (const float*)d_in[0];
    const float* delays = (const float*)d_in[1];
    const float* rtts   = (const float*)d_in[2];
    float* out = (float*)d_out;
    int rows = in_sizes[0] / S_LEN;   // B = 2048
    traffic_kernel<<<rows, BLOCK, 0, stream>>>(x, delays, rtts, out);
}

// Round 4
// 179.919 us; speedup vs baseline: 2.2439x; 1.1636x over previous
//
#include <hip/hip_runtime.h>
#include <math.h>

// TrafficAugmentation R4. One block per row (S=4096), 512 threads, PER=8.
// - 512 threads + VGPR<=64 + LDS 26.1 KB -> 4 blocks/CU = 32 waves = 100% occ.
// - Phase 1: cyclic ownership (thread t owns {t+512i}), 8-ahead windows with
//   ping-pong round-1 prefetch: ~90% of walks terminate in the prefetched
//   window (zero dependent-LDS latency); survivors take a lockstep 8-ahead
//   tail. Serial fp32 subtract order preserved exactly (chained subs, first
//   k with r_k<=0).
// - Phases 2-4: blocked mapping (thread t = segment [8t,8t+8)); exit-
//   compressed 9-round pointer doubling (512 segments); output built in LDS.
// Exactness: r-=d[j] serial order; burst sums serial increasing-j;
// rem = buf - nf*1448.0f exact (nf*1448 < 2^24).

#define S_LEN 4096
#define BLOCK 512
#define PER   8
#define MSSF  1448.0f

// LDS: region A = dly f32[4104] (ph0-1) / jmp u16[4097] (ph2) / out f32[4096] (ph4)
#define OFF_A    0
#define OFF_NXT  16416    // u16[4097], s2-swizzled
#define OFF_MRK  24612    // u32[512] per-segment mark bits (8 used)
#define OFF_WS   26660    // i32[8]
#define SMEM_SZ  26696

// u16 swizzle for blocked stride-8 access; preserves bit0 (paired u32 writes
// legal); bijective; fixed point at 4096 (sentinel).
__device__ __forceinline__ int s2i(int p) { return p ^ (((p >> 6) & 15) << 1); }

__global__ __launch_bounds__(BLOCK, 8) void traffic_kernel(
    const float* __restrict__ gx,
    const float* __restrict__ gd,
    const float* __restrict__ gr,
    float* __restrict__ gout)
{
    __shared__ __align__(16) unsigned char smem[SMEM_SZ];
    float*          s_dly = (float*)(smem + OFF_A);
    unsigned short* s_jmp = (unsigned short*)(smem + OFF_A);
    float*          s_out = (float*)(smem + OFF_A);
    unsigned short* s_nxt = (unsigned short*)(smem + OFF_NXT);
    unsigned*       s_mrk = (unsigned*)(smem + OFF_MRK);
    int*            s_ws  = (int*)(smem + OFF_WS);

    const int tid = threadIdx.x;
    const size_t rowoff = (size_t)blockIdx.x * S_LEN;
    const float* px = gx + rowoff;
    const float* pd = gd + rowoff;
    const float* pr = gr + rowoff;

    // ---- Phase 0: stage delays (plain layout); pad 8 with -1e30 so windows
    // past row end never falsely terminate (r - (-1e30) stays > 0).
    {
        const float4* pd4 = (const float4*)pd;
        float4* s4 = (float4*)s_dly;
        for (int q = tid; q < S_LEN / 4; q += BLOCK) s4[q] = pd4[q];
        if (tid < 8) s_dly[S_LEN + tid] = -1.0e30f;
    }
    float rt[PER];
    unsigned alive = 0;
#pragma unroll
    for (int i = 0; i < PER; ++i) rt[i] = pr[tid + (i << 9)];
#pragma unroll
    for (int i = 0; i < PER; ++i) alive |= (px[tid + (i << 9)] > 0.0f) ? (1u << i) : 0u;
    __syncthreads();

    // ---- Phase 1: 8-ahead walks, round-1 prefetched (ping-pong) ----
    float dA[8], dB[8];
#pragma unroll
    for (int q = 0; q < 8; ++q) dA[q] = s_dly[tid + q];   // walk 0 window
#pragma unroll
    for (int i = 0; i < PER; ++i) {
        if (i + 1 < PER) {                                // prefetch walk i+1
            int jn = tid + ((i + 1) << 9);
            if (i & 1) {
#pragma unroll
                for (int q = 0; q < 8; ++q) dA[q] = s_dly[jn + q];
            } else {
#pragma unroll
                for (int q = 0; q < 8; ++q) dB[q] = s_dly[jn + q];
            }
        }
        const float* dc = (i & 1) ? dB : dA;
        int j = tid + (i << 9);
        float r = rt[i];
        float r1 = r  - dc[0];     // exact reference subtract order
        float r2 = r1 - dc[1];
        float r3 = r2 - dc[2];
        float r4 = r3 - dc[3];
        float r5 = r4 - dc[4];
        float r6 = r5 - dc[5];
        float r7 = r6 - dc[6];
        float r8 = r7 - dc[7];
        int kk = (r1 <= 0.0f) ? 1 : (r2 <= 0.0f) ? 2 : (r3 <= 0.0f) ? 3 :
                 (r4 <= 0.0f) ? 4 : (r5 <= 0.0f) ? 5 : (r6 <= 0.0f) ? 6 :
                 (r7 <= 0.0f) ? 7 : (r8 <= 0.0f) ? 8 : 0;
        int nx;
        if (kk) {
            nx = j + kk;
        } else {
            j += 8;
            if (j >= S_LEN) {
                nx = S_LEN;
            } else {
                float rr = r8;
                while (true) {                             // survivor tail (~10%)
                    float e0 = s_dly[j];
                    float e1 = s_dly[j + 1];
                    float e2 = s_dly[j + 2];
                    float e3 = s_dly[j + 3];
                    float e4 = s_dly[j + 4];
                    float e5 = s_dly[j + 5];
                    float e6 = s_dly[j + 6];
                    float e7 = s_dly[j + 7];
                    float q1 = rr - e0;
                    float q2 = q1 - e1;
                    float q3 = q2 - e2;
                    float q4 = q3 - e3;
                    float q5 = q4 - e4;
                    float q6 = q5 - e5;
                    float q7 = q6 - e6;
                    float q8 = q7 - e7;
                    int k2 = (q1 <= 0.0f) ? 1 : (q2 <= 0.0f) ? 2 : (q3 <= 0.0f) ? 3 :
                             (q4 <= 0.0f) ? 4 : (q5 <= 0.0f) ? 5 : (q6 <= 0.0f) ? 6 :
                             (q7 <= 0.0f) ? 7 : (q8 <= 0.0f) ? 8 : 0;
                    if (k2) { nx = j + k2; break; }
                    j += 8;
                    if (j >= S_LEN) { nx = S_LEN; break; }
                    rr = q8;
                }
            }
        }
        if (!((alive >> i) & 1u)) nx = S_LEN;   // dead start: chain stops here
        s_nxt[s2i(tid + (i << 9))] = (unsigned short)nx;
    }
    __syncthreads();

    // ---- Phase 2a: exit compression (thread t = segment [8t,8t+8)) ----
    const int sb = tid << 3;
    int own[PER];
    if (tid == 0) s_jmp[4096] = (unsigned short)4096;     // sentinel
#pragma unroll
    for (int i = PER - 1; i >= 0; --i) {
        int p = sb + i;
        int v = (int)s_nxt[s2i(p)];                        // v > p
        int e = (v >= sb + PER) ? v : (int)s_jmp[s2i(v)];  // own-seg RAW ok
        s_jmp[s2i(p)] = (unsigned short)e;
        own[i] = e;
    }
    s_mrk[tid] = (tid == 0) ? 1u : 0u;                     // mark position 0
    __syncthreads();

    // ---- Phase 2b: 9-round pointer doubling over exit chain (<=512 nodes,
    // <=1 per segment: exit hops strictly increase segment index).
    for (int k = 0; k < 9; ++k) {
        unsigned m = s_mrk[tid];
        int q = -1;
        if (m) {
            int p = sb + (__ffs(m) - 1);
            int e = (int)s_jmp[s2i(p)];
            if (e < S_LEN) q = e;
        }
        int nv[PER];
        if (k < 8) {
#pragma unroll
            for (int i = 0; i < PER; ++i) nv[i] = (int)s_jmp[s2i(own[i])];
        }
        __syncthreads();                                   // round-k reads done
        if (q >= 0) atomicOr(&s_mrk[q >> 3], 1u << (q & 7));
        if (k < 8) {
#pragma unroll
            for (int h = 0; h < PER / 2; ++h) {            // paired u32 writes
                unsigned w = (unsigned)nv[2 * h] | ((unsigned)nv[2 * h + 1] << 16);
                *(unsigned*)&s_jmp[s2i(sb + 2 * h)] = w;
            }
#pragma unroll
            for (int i = 0; i < PER; ++i) own[i] = nv[i];
        }
        __syncthreads();
    }

    // ---- Phase 2c: expand entry mark to burst starts within segment ----
    unsigned lm = 0;
    {
        unsigned m = s_mrk[tid];
        if (m) {
            int p = sb + (__ffs(m) - 1);
            while (p < sb + PER) {
                lm |= 1u << (p - sb);
                p = (int)s_nxt[s2i(p)];
            }
        }
    }

    // ---- Phase 3: burst sums (global x via L1), serial increasing-j ----
    float bsum[PER];
    unsigned use = 0;
    int tsum = 0;
#pragma unroll
    for (int i = 0; i < PER; ++i) {
        float buf = 0.0f;
        int c = 0;
        if ((lm >> i) & 1u) {
            int p = sb + i;
            int e = (int)s_nxt[s2i(p)];
            float xp = px[p];
            if (xp > 0.0f) {
                use |= 1u << i;
                float sum = xp;
                for (int j = p + 1; j < e; ++j) sum += px[j];
                buf = sum;
                int nf = (int)ceilf(buf / MSSF) - 1; if (nf < 0) nf = 0;
                float rem = buf - (float)nf * MSSF;        // exact
                c = nf + (rem > 0.0f ? 1 : 0);
            }
        }
        bsum[i] = buf;
        tsum += c;
    }

    // ---- block exclusive scan of counts (8 waves) ----
    int texcl;
    {
        int lane = tid & 63, wv = tid >> 6;
        int v = tsum;
        for (int off = 1; off < 64; off <<= 1) {
            int u = __shfl_up(v, off, 64);
            if (lane >= off) v += u;
        }
        if (lane == 63) s_ws[wv] = v;
        __syncthreads();
        int woff = 0;
        for (int w = 0; w < wv; ++w) woff += s_ws[w];
        texcl = woff + v - tsum;
    }

    // ---- Phase 4: build output row in A (jmp dead), coalesced store ----
    {
        float4* z4 = (float4*)s_out;
        float4 zz; zz.x = zz.y = zz.z = zz.w = 0.0f;
        for (int q = tid; q < S_LEN / 4; q += BLOCK) z4[q] = zz;
    }
    __syncthreads();
    {
        int o = texcl;
#pragma unroll
        for (int i = 0; i < PER; ++i) {
            if ((use >> i) & 1u) {
                float buf = bsum[i];
                int nf = (int)ceilf(buf / MSSF) - 1; if (nf < 0) nf = 0;
                float rem = buf - (float)nf * MSSF;
                int e = o + nf; if (e > S_LEN) e = S_LEN;  // OOB drop == truncation
                for (int p2 = o; p2 < e; ++p2) s_out[p2] = MSSF;
                int rp = o + nf;
                if (rem > 0.0f && rp < S_LEN) s_out[rp] = rem;
                o += nf + (rem > 0.0f ? 1 : 0);
            }
        }
    }
    __syncthreads();
    {
        float4* po4 = (float4*)(gout + rowoff);
        float4* so4 = (float4*)s_out;
        for (int q = tid; q < S_LEN / 4; q += BLOCK) po4[q] = so4[q];
    }
}

extern "C" void kernel_launch(void* const* d_in, const int* in_sizes, int n_in,
                              void* d_out, int out_size, void* d_ws, size_t ws_size,
                              hipStream_t stream) {
    const float* x      = (const float*)d_in[0];
    const float* delays = (const float*)d_in[1];
    const float* rtts   = (const float*)d_in[2];
    float* out = (float*)d_out;
    int rows = in_sizes[0] / S_LEN;   // B = 2048
    traffic_kernel<<<rows, BLOCK, 0, stream>>>(x, delays, rtts, out);
}

// Round 5
// 177.541 us; speedup vs baseline: 2.2740x; 1.0134x over previous
//
#include <hip/hip_runtime.h>
#include <math.h>

// TrafficAugmentation R5. One block per row (S=4096), 512 threads, PER=8.
// vs R4:
//  - Phase 1 split: pass 1 evaluates all 8 walks' first 8-windows with STATIC
//    addresses (independent LDS loads, no dependent latency); delays > 0 =>
//    r strictly decreasing => termination = count of (r_k > 0), branch-free.
//    Pad is +1e30 so windows past row end self-terminate; min(nx,4096) gives
//    run-off semantics. Pass 2 drains survivors per-lane (flattened): wave
//    pays max of per-lane totals, not 8 x max-per-walk.
//  - Phase 2b ping-pong jump buffers: 1 barrier/round (9 total, was 18).
//    Both buffers overlay the dead dly region; LDS stays 26.7 KB -> 4 blk/CU.
// Exactness: serial fp32 r-=d[j] chain order preserved; burst sums serial
// increasing-j; rem = buf - nf*1448.0f exact (nf*1448 < 2^24).

#define S_LEN 4096
#define BLOCK 512
#define PER   8
#define MSSF  1448.0f

// LDS: region A (16416 B) = dly f32[4104] (ph0-1) / jmpA+jmpB u16[4104] each
// (ph2) / out f32[4096] (ph4).
#define OFF_A    0
#define OFF_JA   0
#define OFF_JB   8208
#define OFF_NXT  16416    // u16[4097], s2-swizzled
#define OFF_MRK  24624    // u32[512] per-segment mark bits (8 used)
#define OFF_WS   26672    // i32[8]
#define SMEM_SZ  26704

// u16 swizzle for blocked stride-8 access; preserves bit0 (paired u32 writes
// legal); bijective; fixed point at 4096 (sentinel).
__device__ __forceinline__ int s2i(int p) { return p ^ (((p >> 6) & 15) << 1); }

__global__ __launch_bounds__(BLOCK, 8) void traffic_kernel(
    const float* __restrict__ gx,
    const float* __restrict__ gd,
    const float* __restrict__ gr,
    float* __restrict__ gout)
{
    __shared__ __align__(16) unsigned char smem[SMEM_SZ];
    float*          s_dly = (float*)(smem + OFF_A);
    unsigned short* s_jA  = (unsigned short*)(smem + OFF_JA);
    unsigned short* s_jB  = (unsigned short*)(smem + OFF_JB);
    float*          s_out = (float*)(smem + OFF_A);
    unsigned short* s_nxt = (unsigned short*)(smem + OFF_NXT);
    unsigned*       s_mrk = (unsigned*)(smem + OFF_MRK);
    int*            s_ws  = (int*)(smem + OFF_WS);

    const int tid = threadIdx.x;
    const size_t rowoff = (size_t)blockIdx.x * S_LEN;
    const float* px = gx + rowoff;
    const float* pd = gd + rowoff;
    const float* pr = gr + rowoff;

    // ---- Phase 0: stage delays (plain); pad +1e30: windows past row end
    // terminate there (delays > 0 keeps r strictly decreasing everywhere).
    {
        const float4* pd4 = (const float4*)pd;
        float4* s4 = (float4*)s_dly;
        for (int q = tid; q < S_LEN / 4; q += BLOCK) s4[q] = pd4[q];
        if (tid < 8) s_dly[S_LEN + tid] = 1.0e30f;
    }
    float rt[PER];
    unsigned alive = 0;
#pragma unroll
    for (int i = 0; i < PER; ++i) rt[i] = pr[tid + (i << 9)];
#pragma unroll
    for (int i = 0; i < PER; ++i) alive |= (px[tid + (i << 9)] > 0.0f) ? (1u << i) : 0u;
    __syncthreads();

    // ---- Phase 1 pass 1: all 8 first-windows (static addresses, ILP) ----
    unsigned surv = 0;
    float rsv[PER];
#pragma unroll
    for (int i = 0; i < PER; ++i) {
        const int p0 = tid + (i << 9);
        const float* dw = s_dly + p0;
        float d0 = dw[0], d1 = dw[1], d2 = dw[2], d3 = dw[3];
        float d4 = dw[4], d5 = dw[5], d6 = dw[6], d7 = dw[7];
        float r1 = rt[i] - d0;          // exact reference subtract order
        float r2 = r1 - d1;
        float r3 = r2 - d2;
        float r4 = r3 - d3;
        float r5 = r4 - d4;
        float r6 = r5 - d5;
        float r7 = r6 - d6;
        float r8 = r7 - d7;
        // r strictly decreasing: first k with r_k<=0  ==  #(r_k>0)+1
        int c = (r1 > 0.0f) + (r2 > 0.0f) + (r3 > 0.0f) + (r4 > 0.0f) +
                (r5 > 0.0f) + (r6 > 0.0f) + (r7 > 0.0f) + (r8 > 0.0f);
        rsv[i] = r8;
        bool al = (alive >> i) & 1u;
        if (al && c == 8) {
            surv |= 1u << i;            // nxt written in pass 2
        } else {
            int nx = al ? (p0 + c + 1) : S_LEN;
            if (nx > S_LEN) nx = S_LEN;
            s_nxt[s2i(p0)] = (unsigned short)nx;
        }
    }

    // ---- Phase 1 pass 2: survivors, per-lane flattened drain ----
    while (surv) {
        int i = __ffs(surv) - 1;
        surv &= surv - 1;
        float rr = rsv[0];
#pragma unroll
        for (int ii = 1; ii < PER; ++ii) rr = (i == ii) ? rsv[ii] : rr;
        int p0 = tid + (i << 9);
        int j = p0 + 8;                  // survivors have p0+8 <= S_LEN
        int nx;
        while (true) {
            float e0 = s_dly[j],     e1 = s_dly[j + 1];
            float e2 = s_dly[j + 2], e3 = s_dly[j + 3];
            float e4 = s_dly[j + 4], e5 = s_dly[j + 5];
            float e6 = s_dly[j + 6], e7 = s_dly[j + 7];
            float q1 = rr - e0;
            float q2 = q1 - e1;
            float q3 = q2 - e2;
            float q4 = q3 - e3;
            float q5 = q4 - e4;
            float q6 = q5 - e5;
            float q7 = q6 - e6;
            float q8 = q7 - e7;
            int c2 = (q1 > 0.0f) + (q2 > 0.0f) + (q3 > 0.0f) + (q4 > 0.0f) +
                     (q5 > 0.0f) + (q6 > 0.0f) + (q7 > 0.0f) + (q8 > 0.0f);
            if (c2 < 8) { nx = j + c2 + 1; break; }   // pad +1e30 forces c2<8 at end
            j += 8;
            rr = q8;
        }
        if (nx > S_LEN) nx = S_LEN;      // run-off-row semantics
        s_nxt[s2i(p0)] = (unsigned short)nx;
    }
    __syncthreads();

    // ---- Phase 2a: exit compression (thread t = segment [8t,8t+8)) ----
    const int sb = tid << 3;
    int own[PER];
    if (tid == 0) { s_jA[4096] = (unsigned short)4096; s_jB[4096] = (unsigned short)4096; }
#pragma unroll
    for (int i = PER - 1; i >= 0; --i) {
        int p = sb + i;
        int v = (int)s_nxt[s2i(p)];                        // v > p
        int e = (v >= sb + PER) ? v : (int)s_jA[s2i(v)];   // own-seg RAW ok
        s_jA[s2i(p)] = (unsigned short)e;
        own[i] = e;
    }
    s_mrk[tid] = (tid == 0) ? 1u : 0u;                     // mark position 0
    __syncthreads();

    // ---- Phase 2b: 9-round pointer doubling, ping-pong (1 barrier/round).
    // Exit chain <=512 nodes, <=1 per segment (hops strictly leave segment).
    {
        unsigned short* ja = s_jA;
        unsigned short* jb = s_jB;
        for (int k = 0; k < 9; ++k) {
            unsigned m = s_mrk[tid];
            int q = -1;
            if (m) {
                int p = sb + (__ffs(m) - 1);
                int e = (int)ja[s2i(p)];
                if (e < S_LEN) q = e;
            }
            if (k < 8) {
                int nv[PER];
#pragma unroll
                for (int i = 0; i < PER; ++i) nv[i] = (int)ja[s2i(own[i])];
#pragma unroll
                for (int h = 0; h < PER / 2; ++h) {        // paired u32 writes
                    unsigned w = (unsigned)nv[2 * h] | ((unsigned)nv[2 * h + 1] << 16);
                    *(unsigned*)&jb[s2i(sb + 2 * h)] = w;
                }
#pragma unroll
                for (int i = 0; i < PER; ++i) own[i] = nv[i];
            }
            if (q >= 0) atomicOr(&s_mrk[q >> 3], 1u << (q & 7));  // late marks seen next round
            __syncthreads();
            unsigned short* t = ja; ja = jb; jb = t;
        }
    }

    // ---- Phase 2c: expand entry mark to burst starts within segment ----
    unsigned lm = 0;
    {
        unsigned m = s_mrk[tid];
        if (m) {
            int p = sb + (__ffs(m) - 1);
            while (p < sb + PER) {
                lm |= 1u << (p - sb);
                p = (int)s_nxt[s2i(p)];
            }
        }
    }

    // ---- Phase 3: burst sums (global x via L1), serial increasing-j ----
    float bsum[PER];
    unsigned use = 0;
    int tsum = 0;
#pragma unroll
    for (int i = 0; i < PER; ++i) {
        float buf = 0.0f;
        int c = 0;
        if ((lm >> i) & 1u) {
            int p = sb + i;
            int e = (int)s_nxt[s2i(p)];
            float xp = px[p];
            if (xp > 0.0f) {
                use |= 1u << i;
                float sum = xp;
                for (int j = p + 1; j < e; ++j) sum += px[j];
                buf = sum;
                int nf = (int)ceilf(buf / MSSF) - 1; if (nf < 0) nf = 0;
                float rem = buf - (float)nf * MSSF;        // exact
                c = nf + (rem > 0.0f ? 1 : 0);
            }
        }
        bsum[i] = buf;
        tsum += c;
    }

    // ---- block exclusive scan of counts (8 waves) ----
    int texcl;
    {
        int lane = tid & 63, wv = tid >> 6;
        int v = tsum;
        for (int off = 1; off < 64; off <<= 1) {
            int u = __shfl_up(v, off, 64);
            if (lane >= off) v += u;
        }
        if (lane == 63) s_ws[wv] = v;
        __syncthreads();
        int woff = 0;
        for (int w = 0; w < wv; ++w) woff += s_ws[w];
        texcl = woff + v - tsum;
    }

    // ---- Phase 4: build output row in A (jump buffers dead), store ----
    {
        float4* z4 = (float4*)s_out;
        float4 zz; zz.x = zz.y = zz.z = zz.w = 0.0f;
        for (int q = tid; q < S_LEN / 4; q += BLOCK) z4[q] = zz;
    }
    __syncthreads();
    {
        int o = texcl;
#pragma unroll
        for (int i = 0; i < PER; ++i) {
            if ((use >> i) & 1u) {
                float buf = bsum[i];
                int nf = (int)ceilf(buf / MSSF) - 1; if (nf < 0) nf = 0;
                float rem = buf - (float)nf * MSSF;
                int e = o + nf; if (e > S_LEN) e = S_LEN;  // OOB drop == truncation
                for (int p2 = o; p2 < e; ++p2) s_out[p2] = MSSF;
                int rp = o + nf;
                if (rem > 0.0f && rp < S_LEN) s_out[rp] = rem;
                o += nf + (rem > 0.0f ? 1 : 0);
            }
        }
    }
    __syncthreads();
    {
        float4* po4 = (float4*)(gout + rowoff);
        float4* so4 = (float4*)s_out;
        for (int q = tid; q < S_LEN / 4; q += BLOCK) po4[q] = so4[q];
    }
}

extern "C" void kernel_launch(void* const* d_in, const int* in_sizes, int n_in,
                              void* d_out, int out_size, void* d_ws, size_t ws_size,
                              hipStream_t stream) {
    const float* x      = (const float*)d_in[0];
    const float* delays = (const float*)d_in[1];
    const float* rtts   = (const float*)d_in[2];
    float* out = (float*)d_out;
    int rows = in_sizes[0] / S_LEN;   // B = 2048
    traffic_kernel<<<rows, BLOCK, 0, stream>>>(x, delays, rtts, out);
}